// Round 3
// baseline (1324.533 us; speedup 1.0000x reference)
//
#include <hip/hip_runtime.h>

// WindowAttentionLite, wave-per-head MFMA, TWO windows per block (8x16 px).
// x(4,256,256,256) fp32, w_qkv(768,256), w_proj(256,256). 128 tokens/block,
// 8 waves, wave g owns head g for both windows. Q/K/V in registers; x and
// attn-out SHARE one LDS buffer (x dead after QKV). All HBM row chunks are
// full 64B segments -> no fetch/write amplification.

#define DIMC 256
#define NH   8
#define HD   32
#define NTOK2 128
#define HRES 256
#define IMG  (HRES * HRES)
#define XP   264   // f16 pitch: 528 B == 16 (mod 128) -> balanced bank quads

typedef _Float16 f16x8 __attribute__((ext_vector_type(8)));
typedef _Float16 f16x4 __attribute__((ext_vector_type(4)));
typedef float    f32x4 __attribute__((ext_vector_type(4)));

#define MFMA(a, b, c) __builtin_amdgcn_mfma_f32_16x16x32_f16((a), (b), (c), 0, 0, 0)

// ---------- prologue: convert weights fp32 -> fp16 into workspace ----------
__global__ __launch_bounds__(256) void cvt_weights(const float* __restrict__ wqkv,
                                                   const float* __restrict__ wproj,
                                                   _Float16* __restrict__ wq,
                                                   _Float16* __restrict__ wp)
{
    int i = blockIdx.x * 256 + threadIdx.x;
    const int NQ = 768 * 256;
    const int NT = NQ + 256 * 256;
    if (i < NQ)      wq[i] = (_Float16)wqkv[i];
    else if (i < NT) wp[i - NQ] = (_Float16)wproj[i - NQ];
}

template <int PRE>
__device__ __forceinline__ f16x8 ldw(const void* w, int idx)
{
    if constexpr (PRE) {
        return *(const f16x8*)((const _Float16*)w + idx);
    } else {
        const float* p = (const float*)w + idx;
        f16x8 r;
        #pragma unroll
        for (int j = 0; j < 8; ++j) r[j] = (_Float16)p[j];
        return r;
    }
}

__device__ __forceinline__ int2 shfl2(int2 v, int s)
{
    v.x = __shfl(v.x, s);
    v.y = __shfl(v.y, s);
    return v;
}

__device__ __forceinline__ int2 pack4(f32x4 a)
{
    f16x4 h;
    h[0] = (_Float16)a[0]; h[1] = (_Float16)a[1];
    h[2] = (_Float16)a[2]; h[3] = (_Float16)a[3];
    return __builtin_bit_cast(int2, h);
}

__device__ __forceinline__ f16x8 cat8(int2 lo, int2 hi)
{
    int4 w = {lo.x, lo.y, hi.x, hi.y};
    return __builtin_bit_cast(f16x8, w);
}

// D-layout packs (col=lane&15, row=4*lq'+r, row-tiles {pu0,pu1}) -> A/B frag
// (lane&15 = col, k = 8*lq + j) via in-wave shuffles.
__device__ __forceinline__ f16x8 bfrag(int2 pu0, int2 pu1, int ln, int lq)
{
    const int slo = ln + 32 * (lq & 1);
    int2 l0 = shfl2(pu0, slo), h0 = shfl2(pu0, slo + 16);
    int2 l1 = shfl2(pu1, slo), h1 = shfl2(pu1, slo + 16);
    int2 lo = (lq & 2) ? l1 : l0;
    int2 hi = (lq & 2) ? h1 : h0;
    return cat8(lo, hi);
}

// LDS index with 16B-slot XOR swizzle (keyed on row>>3): kills the 8-way
// conflict on staging stores (8-row-stride column writes) while keeping
// all reads 2-way-or-free. Only touches col bits 3..5 -> f16x4/f16x8 safe.
__device__ __forceinline__ int swz(int row, int col)
{
    return row * XP + (col ^ (((row >> 3) & 7) << 3));
}

template <int PRE>
__global__ __launch_bounds__(512, 4)
void win_attn_mfma(const float* __restrict__ x,
                   const void* __restrict__ wqkv,
                   const void* __restrict__ wproj,
                   float* __restrict__ out)
{
    __shared__ _Float16 xa[NTOK2 * XP];   // 67.6 KB: x tokens, then attn-out

    const int t  = threadIdx.x;
    const int ln = t & 15;
    const int lq = (t & 63) >> 4;
    const int gu = __builtin_amdgcn_readfirstlane(t >> 6);  // wave id = head id

    // chunked bijective XCD swizzle (nwg = 2048, 256 per XCD): neighbors in w
    // are spatial neighbors -> shared 128B lines hit the same L2.
    const int lin = blockIdx.x + (blockIdx.y << 4) + (blockIdx.z << 9);
    const int w   = ((lin & 7) << 8) | (lin >> 3);
    const int b   = w >> 9;
    const int y0  = ((w >> 4) & 31) * 8;
    const int x0  = (w & 15) * 16;

    const f32x4 zero = {0.f, 0.f, 0.f, 0.f};
    const float scale = 0.17677669529663687f;  // 1/sqrt(32), folded into Q

    // ---- stage x -> xa (token-major fp16): 64B global reads, 8x8 shfl
    // transpose per window, b128 LDS stores.
    {
        const int py = t & 7;
        const int cg = (t >> 3) & 7;
        const float* xb = x + (long)b * DIMC * IMG + (long)(y0 + py) * HRES + x0;
        #pragma unroll
        for (int i = 0; i < 8; ++i) {
            const int win = i & 1;
            const int cb  = (i >> 1) * 64 + gu * 8;
            const float* src = xb + (long)(cb + cg) * IMG + win * 8;
            float4 f0 = *(const float4*)src;
            float4 f1 = *(const float4*)(src + 4);
            float v[8] = {f0.x, f0.y, f0.z, f0.w, f1.x, f1.y, f1.z, f1.w};
            #pragma unroll
            for (int s = 1; s < 8; s <<= 1) {
                float nv[8];
                #pragma unroll
                for (int j = 0; j < 8; ++j) {
                    float ex = __shfl_xor(v[j ^ s], 8 * s);
                    nv[j] = ((j ^ cg) & s) ? ex : v[j];
                }
                #pragma unroll
                for (int j = 0; j < 8; ++j) v[j] = nv[j];
            }
            f16x8 hv;
            #pragma unroll
            for (int j = 0; j < 8; ++j) hv[j] = (_Float16)v[j];
            *(f16x8*)&xa[swz(win * 64 + 8 * py + cg, cb)] = hv;
        }
    }

    int2 Qp[2][4], Kp[2][4], Vp[4][2];

    // ---- QKV for head gu, one window. Q,K: mfma(W,x) -> col=tok, row=d.
    // V: mfma(x,W) -> col=d, row=tok (feeds PV's A operand directly).
    auto qkv_win = [&](int win) {
        #pragma unroll
        for (int mt = 0; mt < 2; ++mt) {
            f32x4 aq[4], ak[4], av[4];
            #pragma unroll
            for (int nt = 0; nt < 4; ++nt) { aq[nt] = zero; ak[nt] = zero; av[nt] = zero; }
            const int rq = (gu * HD + 16 * mt + ln) * DIMC;
            const int rk = rq + DIMC * DIMC;
            const int rv = rk + DIMC * DIMC;
            #pragma unroll
            for (int ks = 0; ks < 8; ++ks) {
                const int co = 32 * ks + 8 * lq;
                f16x8 wqf = ldw<PRE>(wqkv, rq + co);
                f16x8 wkf = ldw<PRE>(wqkv, rk + co);
                f16x8 wvf = ldw<PRE>(wqkv, rv + co);
                #pragma unroll
                for (int nt = 0; nt < 4; ++nt) {
                    f16x8 xf = *(const f16x8*)&xa[swz(win * 64 + 16 * nt + ln, co)];
                    aq[nt] = MFMA(wqf, xf, aq[nt]);
                    ak[nt] = MFMA(wkf, xf, ak[nt]);
                    av[nt] = MFMA(xf, wvf, av[nt]);
                }
            }
            #pragma unroll
            for (int nt = 0; nt < 4; ++nt) {
                Qp[mt][nt] = pack4(aq[nt] * scale);
                Kp[mt][nt] = pack4(ak[nt]);
                Vp[nt][mt] = pack4(av[nt]);
            }
        }
    };

    // ---- attention for head gu, one window: registers + shuffles only.
    auto attn_win = [&](int win) {
        f16x8 kf[4], qf[4];
        #pragma unroll
        for (int kt = 0; kt < 4; ++kt) kf[kt] = bfrag(Kp[0][kt], Kp[1][kt], ln, lq);
        #pragma unroll
        for (int qt = 0; qt < 4; ++qt) qf[qt] = bfrag(Qp[0][qt], Qp[1][qt], ln, lq);

        f32x4 s[4][4];
        #pragma unroll
        for (int kt = 0; kt < 4; ++kt)
            #pragma unroll
            for (int qt = 0; qt < 4; ++qt)
                s[kt][qt] = MFMA(kf[kt], qf[qt], zero);

        float inv[4];
        #pragma unroll
        for (int qt = 0; qt < 4; ++qt) {
            float m = -1e30f;
            #pragma unroll
            for (int kt = 0; kt < 4; ++kt)
                #pragma unroll
                for (int r = 0; r < 4; ++r) m = fmaxf(m, s[kt][qt][r]);
            m = fmaxf(m, __shfl_xor(m, 16));
            m = fmaxf(m, __shfl_xor(m, 32));
            float sum = 0.f;
            #pragma unroll
            for (int kt = 0; kt < 4; ++kt)
                #pragma unroll
                for (int r = 0; r < 4; ++r) {
                    float e = __expf(s[kt][qt][r] - m);
                    s[kt][qt][r] = e;
                    sum += e;
                }
            sum += __shfl_xor(sum, 16);
            sum += __shfl_xor(sum, 32);
            inv[qt] = 1.f / sum;
        }

        int2 Pp[4][4];
        #pragma unroll
        for (int kt = 0; kt < 4; ++kt)
            #pragma unroll
            for (int qt = 0; qt < 4; ++qt)
                Pp[kt][qt] = pack4(s[kt][qt] * inv[qt]);

        f32x4 pv[2][4];
        #pragma unroll
        for (int dt = 0; dt < 2; ++dt)
            #pragma unroll
            for (int qt = 0; qt < 4; ++qt) pv[dt][qt] = zero;
        #pragma unroll
        for (int ks = 0; ks < 2; ++ks) {
            f16x8 vf[2], pf[4];
            #pragma unroll
            for (int dt = 0; dt < 2; ++dt)
                vf[dt] = bfrag(Vp[2 * ks][dt], Vp[2 * ks + 1][dt], ln, lq);
            #pragma unroll
            for (int qt = 0; qt < 4; ++qt)
                pf[qt] = bfrag(Pp[2 * ks][qt], Pp[2 * ks + 1][qt], ln, lq);
            #pragma unroll
            for (int dt = 0; dt < 2; ++dt)
                #pragma unroll
                for (int qt = 0; qt < 4; ++qt)
                    pv[dt][qt] = MFMA(vf[dt], pf[qt], pv[dt][qt]);
        }

        // attn-out overwrites the x buffer: ao[token][gu*32 + d]
        #pragma unroll
        for (int dt = 0; dt < 2; ++dt)
            #pragma unroll
            for (int qt = 0; qt < 4; ++qt) {
                f16x4 hv;
                #pragma unroll
                for (int r = 0; r < 4; ++r) hv[r] = (_Float16)pv[dt][qt][r];
                *(f16x4*)&xa[swz(win * 64 + 16 * qt + ln,
                                 gu * HD + 16 * dt + 4 * lq)] = hv;
            }
    };

    __syncthreads();
    qkv_win(0);                 // reads x rows 0..63
    __syncthreads();
    attn_win(0);                // writes ao rows 0..63 (x rows 0..63 dead)
    qkv_win(1);                 // reads x rows 64..127 (disjoint)
    __syncthreads();
    attn_win(1);                // writes ao rows 64..127
    __syncthreads();

    // ---- proj: OUT[256 x 128] = Wproj * AO, K = 256; 2 o-tiles/wave ----
    f32x4 fa[2][8];
    #pragma unroll
    for (int o = 0; o < 2; ++o)
        #pragma unroll
        for (int nt = 0; nt < 8; ++nt) fa[o][nt] = zero;
    {
        const int r0 = (16 * (2 * gu + 0) + ln) * DIMC;
        const int r1 = (16 * (2 * gu + 1) + ln) * DIMC;
        #pragma unroll
        for (int ks = 0; ks < 8; ++ks) {
            const int co = 32 * ks + 8 * lq;
            f16x8 w0 = ldw<PRE>(wproj, r0 + co);
            f16x8 w1 = ldw<PRE>(wproj, r1 + co);
            #pragma unroll
            for (int nt = 0; nt < 8; ++nt) {
                f16x8 af = *(const f16x8*)&xa[swz(16 * nt + ln, co)];
                fa[0][nt] = MFMA(w0, af, fa[0][nt]);
                fa[1][nt] = MFMA(w1, af, fa[1][nt]);
            }
        }
    }

    // ---- epilogue: D col=token(ln), row=och(4*lq+r); channel-major out.
    // Block covers 16 consecutive px -> full 64B lines per (och,row).
    {
        float* ob = out + (long)b * DIMC * IMG + (long)y0 * HRES + x0;
        #pragma unroll
        for (int o = 0; o < 2; ++o)
            #pragma unroll
            for (int nt = 0; nt < 8; ++nt) {
                const int och = 16 * (2 * gu + o) + 4 * lq;
                const int tok = 16 * nt + ln;
                const int win = tok >> 6, py = (tok >> 3) & 7, px = tok & 7;
                float* op = ob + (long)och * IMG + py * HRES + win * 8 + px;
                #pragma unroll
                for (int r = 0; r < 4; ++r) op[(long)r * IMG] = fa[o][nt][r];
            }
    }
}

extern "C" void kernel_launch(void* const* d_in, const int* in_sizes, int n_in,
                              void* d_out, int out_size, void* d_ws, size_t ws_size,
                              hipStream_t stream)
{
    const float* x      = (const float*)d_in[0];
    const float* w_qkv  = (const float*)d_in[1];
    const float* w_proj = (const float*)d_in[2];
    float* out          = (float*)d_out;

    dim3 grid(HRES / 16, HRES / 8, 4);   // (16, 32, 4) = 2048 blocks
    dim3 block(512);

    const size_t need = (size_t)(768 * 256 + 256 * 256) * sizeof(_Float16);
    if (d_ws && ws_size >= need) {
        _Float16* wq = (_Float16*)d_ws;
        _Float16* wp = wq + 768 * 256;
        hipLaunchKernelGGL(cvt_weights, dim3(1024), dim3(256), 0, stream,
                           w_qkv, w_proj, wq, wp);
        hipLaunchKernelGGL((win_attn_mfma<1>), grid, block, 0, stream,
                           x, (const void*)wq, (const void*)wp, out);
    } else {
        hipLaunchKernelGGL((win_attn_mfma<0>), grid, block, 0, stream,
                           x, (const void*)w_qkv, (const void*)w_proj, out);
    }
}